// Round 2
// baseline (388.022 us; speedup 1.0000x reference)
//
#include <hip/hip_runtime.h>

// out[b,t] = sum_d x[b,t,d] * stimulus[b,t,d]
// 65536 rows of 768 fp32. One 64-lane wave per 8 consecutive rows:
// 6 float4 loads per row per lane (48 independent loads/wave for MLP),
// 8 independent accumulators, post-loop butterfly reductions (8 independent
// shuffle chains), lane 0 writes 8 results as two float4 stores.

constexpr int D4   = 768 / 4;      // 192 float4 per row
constexpr int ROWS = 8 * 8192;     // 65536
constexpr int RPW  = 8;            // rows per wave

__global__ __launch_bounds__(256, 8) void row_dot_kernel(
    const float4* __restrict__ x,
    const float4* __restrict__ s,
    float4* __restrict__ out4)
{
    const int wave = (blockIdx.x * blockDim.x + threadIdx.x) >> 6;
    const int lane = threadIdx.x & 63;

    const size_t row0 = (size_t)wave * RPW;

    float acc[RPW];
#pragma unroll
    for (int r = 0; r < RPW; ++r) {
        const size_t base = (row0 + r) * D4 + lane;
        float4 a0 = x[base];
        float4 b0 = s[base];
        float4 a1 = x[base + 64];
        float4 b1 = s[base + 64];
        float4 a2 = x[base + 128];
        float4 b2 = s[base + 128];
        float t = 0.0f;
        t = fmaf(a0.x, b0.x, t);
        t = fmaf(a0.y, b0.y, t);
        t = fmaf(a0.z, b0.z, t);
        t = fmaf(a0.w, b0.w, t);
        t = fmaf(a1.x, b1.x, t);
        t = fmaf(a1.y, b1.y, t);
        t = fmaf(a1.z, b1.z, t);
        t = fmaf(a1.w, b1.w, t);
        t = fmaf(a2.x, b2.x, t);
        t = fmaf(a2.y, b2.y, t);
        t = fmaf(a2.z, b2.z, t);
        t = fmaf(a2.w, b2.w, t);
        acc[r] = t;
    }

    // 8 independent 64-lane butterfly reductions (chains overlap).
#pragma unroll
    for (int r = 0; r < RPW; ++r) {
        float v = acc[r];
#pragma unroll
        for (int off = 32; off > 0; off >>= 1)
            v += __shfl_xor(v, off, 64);
        acc[r] = v;
    }

    if (lane == 0) {
        float4 o0 = make_float4(acc[0], acc[1], acc[2], acc[3]);
        float4 o1 = make_float4(acc[4], acc[5], acc[6], acc[7]);
        out4[(size_t)wave * 2]     = o0;
        out4[(size_t)wave * 2 + 1] = o1;
    }
}

extern "C" void kernel_launch(void* const* d_in, const int* in_sizes, int n_in,
                              void* d_out, int out_size, void* d_ws, size_t ws_size,
                              hipStream_t stream)
{
    const float4* x = (const float4*)d_in[0];
    const float4* s = (const float4*)d_in[1];
    float4* out4 = (float4*)d_out;

    // 65536 rows / 8 rows-per-wave = 8192 waves; 4 waves per 256-thread block.
    const int blocks = (ROWS / RPW) / 4;   // 2048
    row_dot_kernel<<<blocks, 256, 0, stream>>>(x, s, out4);
}